// Round 1
// baseline (953.965 us; speedup 1.0000x reference)
//
#include <hip/hip_runtime.h>
#include <math.h>

#define NM 65536
#define NB 128
#define NU 256
#define ND 512

// ---- output layout (flat f32, reference return order) ----
constexpr size_t OUT_READ = 0;                      // [B,U]    32768
constexpr size_t OUT_MEM  = 32768;                  // [M,U]    16777216
constexpr size_t OUT_CWU  = OUT_MEM + 16777216;     // [M,B]    8388608
constexpr size_t OUT_CWLU = OUT_CWU + 8388608;      // [M,B]
constexpr size_t OUT_CWR  = OUT_CWLU + 8388608;     // [M,B]
constexpr size_t OUT_KEY  = OUT_CWR + 8388608;      // [B,U]
constexpr size_t OUT_CC   = OUT_KEY + 32768;        // [B,U]

// ---- ws layout (bytes) ----
constexpr size_t WS_KLNT   = 0;        // 32768 f32 (klnT[u][b])
constexpr size_t WS_MINENC = 131072;   // 128 u64
constexpr size_t WS_MINS   = 132096;   // 128 f32
constexpr size_t WS_ISTAR  = 132608;   // 1 u32
constexpr size_t WS_PART   = 135168;   // optional: 256 * 32768 f32 partials

__device__ __forceinline__ unsigned fenc(float x) {
    unsigned u = __float_as_uint(x);
    return (u & 0x80000000u) ? ~u : (u | 0x80000000u);
}
__device__ __forceinline__ float fdec(unsigned e) {
    unsigned u = (e & 0x80000000u) ? (e ^ 0x80000000u) : ~e;
    return __uint_as_float(u);
}
__device__ __forceinline__ float sigm(float x) { return 1.0f / (1.0f + expf(-x)); }

// ---------------- K1: LSTM controller + normalized keys ----------------
__global__ __launch_bounds__(256) void k_lstm(
    const float* __restrict__ xin_g, const float* __restrict__ r_tm1,
    const float* __restrict__ h_tm1, const float* __restrict__ cc_tm1,
    const float* __restrict__ Wk, const float* __restrict__ Wr,
    const float* __restrict__ bias, float* __restrict__ out,
    float* __restrict__ klnT, unsigned long long* __restrict__ minenc)
{
    const int b = blockIdx.x, t = threadIdx.x;
    __shared__ float xin[ND + NU];
    __shared__ float hh[NU];
    __shared__ float red[NU];
    for (int k = t; k < ND; k += 256) xin[k] = xin_g[b * ND + k];
    xin[ND + t] = r_tm1[b * NU + t];
    hh[t] = h_tm1[b * NU + t];
    out[OUT_READ + b * NU + t] = 0.f;              // zero read region each launch
    if (b == 0 && t < NB) minenc[t] = ~0ULL;       // init argmin atomics
    __syncthreads();

    float zi = bias[t], zf = bias[NU + t], zc = bias[2 * NU + t], zo = bias[3 * NU + t];
    #pragma unroll 4
    for (int k = 0; k < ND + NU; ++k) {
        const float x = xin[k];
        const float* w = Wk + (size_t)k * (4 * NU);
        zi += x * w[t]; zf += x * w[NU + t]; zc += x * w[2 * NU + t]; zo += x * w[3 * NU + t];
    }
    #pragma unroll 4
    for (int k = 0; k < NU; ++k) {
        const float x = hh[k];
        const float* w = Wr + (size_t)k * (4 * NU);
        zi += x * w[t]; zf += x * w[NU + t]; zc += x * w[2 * NU + t]; zo += x * w[3 * NU + t];
    }
    const float gi = sigm(zi), gf = sigm(zf), gc = tanhf(zc), go = sigm(zo);
    const float cold = cc_tm1[b * NU + t];
    const float cn = __fadd_rn(__fmul_rn(gf, cold), __fmul_rn(gi, gc));
    const float hn = __fmul_rn(go, tanhf(cn));
    out[OUT_KEY + b * NU + t] = hn;
    out[OUT_CC + b * NU + t] = cn;
    red[t] = hn * hn;
    __syncthreads();
    for (int s = 128; s > 0; s >>= 1) { if (t < s) red[t] += red[t + s]; __syncthreads(); }
    const float nrm = sqrtf(fmaxf(red[0], 1e-12f));
    klnT[t * NB + b] = hn / nrm;   // transposed [u][b]
}

// ------------- K2: cosine addressing + batch-softmax + usage -------------
__global__ __launch_bounds__(256, 1) void k_addr(
    const float* __restrict__ mT,
    const float* __restrict__ cwr_t, const float* __restrict__ cwlu_t,
    const float* __restrict__ cwu_t, const float* __restrict__ wgp,
    const float* __restrict__ klnT, float* __restrict__ out,
    unsigned long long* __restrict__ minenc)
{
    __shared__ float kln[NU * NB];      // [u][b], 128 KB
    __shared__ float mrow[4][264];      // per-wave row stage (16B-aligned stride)
    const int t = threadIdx.x, w = t >> 6, l = t & 63;
    for (int i = t; i < NU * NB / 4; i += 256)
        ((float4*)kln)[i] = ((const float4*)klnT)[i];
    __syncthreads();

    const float wg = sigm(wgp[0]);
    const float omw = __fsub_rn(1.f, wg);
    const int base = blockIdx.x * 256 + w * 64;

    // prefetch slot 0
    size_t m0 = (size_t)base;
    float4 mv_n = *(const float4*)(mT + m0 * NU + l * 4);
    float2 wrt_n = ((const float2*)(cwr_t + m0 * NB))[l];
    float2 wlu_n = ((const float2*)(cwlu_t + m0 * NB))[l];
    float2 wut_n = ((const float2*)(cwu_t + m0 * NB))[l];
    unsigned long long lmin0 = ~0ULL, lmin1 = ~0ULL;

    for (int i = 0; i < 64; ++i) {
        const int m = base + i;
        const float4 mv = mv_n;
        const float2 wrt = wrt_n, wlu = wlu_n, wut = wut_n;
        if (i + 1 < 64) {  // prefetch next slot (hides HBM latency at 1 wave/SIMD)
            const size_t mn = (size_t)m + 1;
            mv_n  = *(const float4*)(mT + mn * NU + l * 4);
            wrt_n = ((const float2*)(cwr_t + mn * NB))[l];
            wlu_n = ((const float2*)(cwlu_t + mn * NB))[l];
            wut_n = ((const float2*)(cwu_t + mn * NB))[l];
        }
        float ss = mv.x * mv.x + mv.y * mv.y + mv.z * mv.z + mv.w * mv.w;
        #pragma unroll
        for (int d = 1; d < 64; d <<= 1) ss += __shfl_xor(ss, d);
        const float rn = sqrtf(fmaxf(ss, 1e-12f));

        ((float4*)mrow[w])[l] = mv;     // wave-private LDS stage (DS ops in-order per wave)
        float acc0 = 0.f, acc1 = 0.f;
        #pragma unroll 8
        for (int u = 0; u < NU; ++u) {
            const float muv = mrow[w][u];                    // broadcast read
            const float2 kv = ((const float2*)kln)[u * 64 + l];
            acc0 += muv * kv.x; acc1 += muv * kv.y;
        }
        const float c0 = acc0 / rn, c1 = acc1 / rn;          // cos for b=2l, 2l+1

        // softmax over batch axis (128 values across this wave)
        float mx = fmaxf(c0, c1);
        #pragma unroll
        for (int d = 1; d < 64; d <<= 1) mx = fmaxf(mx, __shfl_xor(mx, d));
        const float e0 = expf(c0 - mx), e1 = expf(c1 - mx);
        float s = e0 + e1;
        #pragma unroll
        for (int d = 1; d < 64; d <<= 1) s += __shfl_xor(s, d);
        const float w0 = e0 / s, w1 = e1 / s;

        const float cww0 = __fadd_rn(__fadd_rn(__fmul_rn(wg, wrt.x), omw), wlu.x);
        const float cww1 = __fadd_rn(__fadd_rn(__fmul_rn(wg, wrt.y), omw), wlu.y);
        const float cu0 = __fadd_rn(__fadd_rn(__fmul_rn(0.95f, wut.x), w0), cww0);
        const float cu1 = __fadd_rn(__fadd_rn(__fmul_rn(0.95f, wut.y), w1), cww1);

        ((float2*)(out + OUT_CWR))[(size_t)m * 64 + l] = make_float2(w0, w1);
        ((float2*)(out + OUT_CWU))[(size_t)m * 64 + l] = make_float2(cu0, cu1);

        const unsigned long long e0u = (((unsigned long long)fenc(cu0)) << 32) | (unsigned)m;
        const unsigned long long e1u = (((unsigned long long)fenc(cu1)) << 32) | (unsigned)m;
        lmin0 = (e0u < lmin0) ? e0u : lmin0;
        lmin1 = (e1u < lmin1) ? e1u : lmin1;
    }
    atomicMin(&minenc[2 * l], lmin0);
    atomicMin(&minenc[2 * l + 1], lmin1);
}

// ---------------- K3: global argmin (first-occurrence) ----------------
__global__ void k_argmin(const unsigned long long* __restrict__ minenc,
                         float* __restrict__ mins, unsigned* __restrict__ istar)
{
    __shared__ unsigned long long red[NB];
    const int t = threadIdx.x;
    const unsigned long long e = minenc[t];
    const unsigned enc32 = (unsigned)(e >> 32);
    mins[t] = fdec(enc32);
    red[t] = (((unsigned long long)enc32) << 32) | (unsigned)t;
    __syncthreads();
    for (int s = 64; s > 0; s >>= 1) {
        if (t < s) { const unsigned long long o = red[t + s]; if (o < red[t]) red[t] = o; }
        __syncthreads();
    }
    if (t == 0) {
        const unsigned bstar = (unsigned)(red[0] & 0xFFFFFFFFu);
        istar[0] = (unsigned)(minenc[bstar] & 0xFFFFFFFFu);
    }
}

// -------- K4: c_wlu + memory update + read-GEMM accumulation --------
template <int USE_PART>
__global__ __launch_bounds__(256, 1) void k_final(
    const float* __restrict__ mT,
    const float* __restrict__ cwr_t, const float* __restrict__ cwlu_t,
    const float* __restrict__ wgp, const float* __restrict__ mins,
    const unsigned* __restrict__ istar_p,
    float* __restrict__ out, float* __restrict__ part)
{
    __shared__ float key[NB * NU];      // key_list [b][u], 128 KB
    __shared__ float2 cwb[2][NB];       // (c_ww, c_wr) double-buffered
    __shared__ float minsb[NB];
    const int t = threadIdx.x;
    for (int i = t; i < NB * NU / 4; i += 256)
        ((float4*)key)[i] = ((const float4*)(out + OUT_KEY))[i];
    if (t < NB) minsb[t] = mins[t];
    const float wg = sigm(wgp[0]);
    const float omw = __fsub_rn(1.f, wg);
    const int istar = (int)istar_p[0];

    float racc[NB];
    #pragma unroll
    for (int b = 0; b < NB; ++b) racc[b] = 0.f;

    const int base = blockIdx.x * 256;
    // prefetch slot 0
    float p_wr = 0.f, p_wu = 0.f, p_wrt = 0.f, p_wlu = 0.f;
    if (t < NB) {
        p_wr  = out[OUT_CWR + (size_t)base * NB + t];
        p_wu  = out[OUT_CWU + (size_t)base * NB + t];
        p_wrt = cwr_t[(size_t)base * NB + t];
        p_wlu = cwlu_t[(size_t)base * NB + t];
    }
    float p_m = mT[(size_t)base * NU + t];

    for (int i = 0; i < 256; ++i) {
        const int m = base + i;
        const int buf = i & 1;
        const float wrv = p_wr, wuv = p_wu, wrtv = p_wrt, wluv = p_wlu, mval = p_m;
        if (i + 1 < 256) {  // prefetch next slot before compute
            const size_t mn = (size_t)m + 1;
            if (t < NB) {
                p_wr  = out[OUT_CWR + mn * NB + t];
                p_wu  = out[OUT_CWU + mn * NB + t];
                p_wrt = cwr_t[mn * NB + t];
                p_wlu = cwlu_t[mn * NB + t];
            }
            p_m = mT[mn * NU + t];
        }
        if (t < NB) {
            const float cww = __fadd_rn(__fadd_rn(__fmul_rn(wg, wrtv), omw), wluv);
            cwb[buf][t] = make_float2(cww, wrv);
            out[OUT_CWLU + (size_t)m * NB + t] = (wuv <= minsb[t]) ? 1.f : 0.f;
        }
        __syncthreads();
        float mem = (m == istar) ? 0.f : 128.f * mval;
        #pragma unroll
        for (int b = 0; b < NB; ++b) {
            const float2 cw = cwb[buf][b];
            mem += cw.x * key[b * NU + t];
            racc[b] += cw.y * mval;
        }
        out[OUT_MEM + (size_t)m * NU + t] = mem;
    }

    if (USE_PART) {
        float* dst = part + (size_t)blockIdx.x * (NB * NU);
        #pragma unroll
        for (int b = 0; b < NB; ++b) dst[b * NU + t] = racc[b];
    } else {
        #pragma unroll
        for (int b = 0; b < NB; ++b) atomicAdd(out + OUT_READ + b * NU + t, racc[b]);
    }
}

// ---------------- K5: deterministic read reduction ----------------
__global__ __launch_bounds__(256) void k_redread(const float* __restrict__ part,
                                                 float* __restrict__ out)
{
    const int j = blockIdx.x * 256 + threadIdx.x;
    float s = 0.f;
    #pragma unroll 4
    for (int blk = 0; blk < 256; ++blk) s += part[(size_t)blk * (NB * NU) + j];
    out[OUT_READ + j] = s;
}

extern "C" void kernel_launch(void* const* d_in, const int* in_sizes, int n_in,
                              void* d_out, int out_size, void* d_ws, size_t ws_size,
                              hipStream_t stream)
{
    const float* inputs    = (const float*)d_in[0];
    const float* r_tm1     = (const float*)d_in[1];
    const float* m_tm1     = (const float*)d_in[2];
    const float* c_wu_tm1  = (const float*)d_in[3];
    const float* c_wlu_tm1 = (const float*)d_in[4];
    const float* c_wr_tm1  = (const float*)d_in[5];
    const float* h_tm1     = (const float*)d_in[6];
    const float* cc_tm1    = (const float*)d_in[7];
    const float* Wk        = (const float*)d_in[8];
    const float* Wr        = (const float*)d_in[9];
    const float* bias      = (const float*)d_in[10];
    const float* wgate     = (const float*)d_in[11];
    float* out = (float*)d_out;
    char* ws = (char*)d_ws;

    float* klnT = (float*)(ws + WS_KLNT);
    unsigned long long* minenc = (unsigned long long*)(ws + WS_MINENC);
    float* mins = (float*)(ws + WS_MINS);
    unsigned* istar = (unsigned*)(ws + WS_ISTAR);
    float* part = (float*)(ws + WS_PART);
    const bool use_part = ws_size >= WS_PART + (size_t)256 * NB * NU * 4;

    hipLaunchKernelGGL(k_lstm, dim3(128), dim3(256), 0, stream,
                       inputs, r_tm1, h_tm1, cc_tm1, Wk, Wr, bias, out, klnT, minenc);
    hipLaunchKernelGGL(k_addr, dim3(256), dim3(256), 0, stream,
                       m_tm1, c_wr_tm1, c_wlu_tm1, c_wu_tm1, wgate, klnT, out, minenc);
    hipLaunchKernelGGL(k_argmin, dim3(1), dim3(128), 0, stream, minenc, mins, istar);
    if (use_part) {
        hipLaunchKernelGGL((k_final<1>), dim3(256), dim3(256), 0, stream,
                           m_tm1, c_wr_tm1, c_wlu_tm1, wgate, mins, istar, out, part);
        hipLaunchKernelGGL(k_redread, dim3(128), dim3(256), 0, stream, part, out);
    } else {
        hipLaunchKernelGGL((k_final<0>), dim3(256), dim3(256), 0, stream,
                           m_tm1, c_wr_tm1, c_wlu_tm1, wgate, mins, istar, out, part);
    }
}

// Round 2
// 525.034 us; speedup vs baseline: 1.8170x; 1.8170x over previous
//
#include <hip/hip_runtime.h>
#include <math.h>

#define NM 65536
#define NB 128
#define NU 256
#define ND 512

// ---- output layout (flat f32, reference return order) ----
constexpr size_t OUT_READ = 0;                      // [B,U]    32768
constexpr size_t OUT_MEM  = 32768;                  // [M,U]    16777216
constexpr size_t OUT_CWU  = OUT_MEM + 16777216;     // [M,B]    8388608
constexpr size_t OUT_CWLU = OUT_CWU + 8388608;      // [M,B]
constexpr size_t OUT_CWR  = OUT_CWLU + 8388608;     // [M,B]
constexpr size_t OUT_KEY  = OUT_CWR + 8388608;      // [B,U]
constexpr size_t OUT_CC   = OUT_KEY + 32768;        // [B,U]

// ---- ws layout (bytes) ----
constexpr size_t WS_KLNT   = 0;        // 32768 f32 (klnT[u][b])
constexpr size_t WS_MINENC = 131072;   // 128 u64
constexpr size_t WS_MINS   = 132096;   // 128 f32
constexpr size_t WS_ISTAR  = 132608;   // 1 u32
constexpr size_t WS_PART   = 135168;   // 256 * 16384 f32 read-partials (16 MB)

__device__ __forceinline__ unsigned fenc(float x) {
    unsigned u = __float_as_uint(x);
    return (u & 0x80000000u) ? ~u : (u | 0x80000000u);
}
__device__ __forceinline__ float fdec(unsigned e) {
    unsigned u = (e & 0x80000000u) ? (e ^ 0x80000000u) : ~e;
    return __uint_as_float(u);
}
__device__ __forceinline__ float sigm(float x) { return 1.0f / (1.0f + expf(-x)); }

// ---------------- K1: LSTM controller + normalized keys (UNCHANGED, numerics anchor) ----------------
__global__ __launch_bounds__(256) void k_lstm(
    const float* __restrict__ xin_g, const float* __restrict__ r_tm1,
    const float* __restrict__ h_tm1, const float* __restrict__ cc_tm1,
    const float* __restrict__ Wk, const float* __restrict__ Wr,
    const float* __restrict__ bias, float* __restrict__ out,
    float* __restrict__ klnT, unsigned long long* __restrict__ minenc)
{
    const int b = blockIdx.x, t = threadIdx.x;
    __shared__ float xin[ND + NU];
    __shared__ float hh[NU];
    __shared__ float red[NU];
    for (int k = t; k < ND; k += 256) xin[k] = xin_g[b * ND + k];
    xin[ND + t] = r_tm1[b * NU + t];
    hh[t] = h_tm1[b * NU + t];
    out[OUT_READ + b * NU + t] = 0.f;              // zero read region each launch
    if (b == 0 && t < NB) minenc[t] = ~0ULL;       // init argmin atomics
    __syncthreads();

    float zi = bias[t], zf = bias[NU + t], zc = bias[2 * NU + t], zo = bias[3 * NU + t];
    #pragma unroll 4
    for (int k = 0; k < ND + NU; ++k) {
        const float x = xin[k];
        const float* w = Wk + (size_t)k * (4 * NU);
        zi += x * w[t]; zf += x * w[NU + t]; zc += x * w[2 * NU + t]; zo += x * w[3 * NU + t];
    }
    #pragma unroll 4
    for (int k = 0; k < NU; ++k) {
        const float x = hh[k];
        const float* w = Wr + (size_t)k * (4 * NU);
        zi += x * w[t]; zf += x * w[NU + t]; zc += x * w[2 * NU + t]; zo += x * w[3 * NU + t];
    }
    const float gi = sigm(zi), gf = sigm(zf), gc = tanhf(zc), go = sigm(zo);
    const float cold = cc_tm1[b * NU + t];
    const float cn = __fadd_rn(__fmul_rn(gf, cold), __fmul_rn(gi, gc));
    const float hn = __fmul_rn(go, tanhf(cn));
    out[OUT_KEY + b * NU + t] = hn;
    out[OUT_CC + b * NU + t] = cn;
    red[t] = hn * hn;
    __syncthreads();
    for (int s = 128; s > 0; s >>= 1) { if (t < s) red[t] += red[t + s]; __syncthreads(); }
    const float nrm = sqrtf(fmaxf(red[0], 1e-12f));
    klnT[t * NB + b] = hn / nrm;   // transposed [u][b]
}

// ------------- K2: cosine addressing + batch-softmax + usage -------------
// 4 slots in flight per wave; per-slot FMA/shuffle sequences bit-identical to R1.
__global__ __launch_bounds__(256, 1) void k_addr(
    const float* __restrict__ mT,
    const float* __restrict__ cwr_t, const float* __restrict__ cwlu_t,
    const float* __restrict__ cwu_t, const float* __restrict__ wgp,
    const float* __restrict__ klnT, float* __restrict__ out,
    unsigned long long* __restrict__ minenc)
{
    __shared__ float4 kln4[128 * 64];   // [u2][l] = (k[2u2][2l],k[2u2][2l+1],k[2u2+1][2l],k[2u2+1][2l+1]), 128KB
    __shared__ float m_ch[4][4][NU];    // wave-private 4-slot rows, 16KB
    const int t = threadIdx.x, w = t >> 6, l = t & 63;
    for (int idx = t; idx < 128 * 64; idx += 256) {
        const int u2 = idx >> 6, ll = idx & 63;
        const float2 a = ((const float2*)(klnT + (size_t)(2 * u2) * NB))[ll];
        const float2 b = ((const float2*)(klnT + (size_t)(2 * u2 + 1) * NB))[ll];
        kln4[idx] = make_float4(a.x, a.y, b.x, b.y);
    }
    __syncthreads();

    const float wg = sigm(wgp[0]);
    const float omw = __fsub_rn(1.f, wg);
    const int wbase = blockIdx.x * 256 + w * 64;
    unsigned long long lmin0 = ~0ULL, lmin1 = ~0ULL;

    // prefetch pass 0
    float4 mv[4]; float2 wrt[4], wlu[4], wut[4];
    #pragma unroll
    for (int j = 0; j < 4; ++j) {
        const size_t s = (size_t)(wbase + j);
        mv[j]  = *(const float4*)(mT + s * NU + l * 4);
        wrt[j] = ((const float2*)(cwr_t + s * NB))[l];
        wlu[j] = ((const float2*)(cwlu_t + s * NB))[l];
        wut[j] = ((const float2*)(cwu_t + s * NB))[l];
    }

    for (int p = 0; p < 16; ++p) {
        const int sbase = wbase + p * 4;
        // norms (exact R1 order: per-lane float4 products, then 64-lane xor tree)
        float rn[4];
        #pragma unroll
        for (int j = 0; j < 4; ++j) {
            float ss = mv[j].x * mv[j].x + mv[j].y * mv[j].y + mv[j].z * mv[j].z + mv[j].w * mv[j].w;
            #pragma unroll
            for (int d = 1; d < 64; d <<= 1) ss += __shfl_xor(ss, d);
            rn[j] = sqrtf(fmaxf(ss, 1e-12f));
            ((float4*)m_ch[w][j])[l] = mv[j];   // wave-private stage (DS in-order per wave)
        }
        float2 cwrt[4], cwluv[4], cwutv[4];
        #pragma unroll
        for (int j = 0; j < 4; ++j) { cwrt[j] = wrt[j]; cwluv[j] = wlu[j]; cwutv[j] = wut[j]; }
        if (p < 15) {   // prefetch next pass (latency hidden under dot loop)
            #pragma unroll
            for (int j = 0; j < 4; ++j) {
                const size_t s = (size_t)(sbase + 4 + j);
                mv[j]  = *(const float4*)(mT + s * NU + l * 4);
                wrt[j] = ((const float2*)(cwr_t + s * NB))[l];
                wlu[j] = ((const float2*)(cwlu_t + s * NB))[l];
                wut[j] = ((const float2*)(cwu_t + s * NB))[l];
            }
        }
        // dot: per slot identical FMA sequence to R1 (u ascending, acc0/acc1 chains)
        float a0[4] = {0.f, 0.f, 0.f, 0.f}, a1[4] = {0.f, 0.f, 0.f, 0.f};
        for (int u2 = 0; u2 < 128; ++u2) {
            const float4 kv = kln4[u2 * 64 + l];
            #pragma unroll
            for (int j = 0; j < 4; ++j) {
                const float2 mm = ((const float2*)m_ch[w][j])[u2];
                a0[j] += mm.x * kv.x; a1[j] += mm.x * kv.y;
                a0[j] += mm.y * kv.z; a1[j] += mm.y * kv.w;
            }
        }
        // softmax + usage + outputs (bit-identical sequences to R1)
        #pragma unroll
        for (int j = 0; j < 4; ++j) {
            const int m = sbase + j;
            const float c0 = a0[j] / rn[j], c1 = a1[j] / rn[j];
            float mx = fmaxf(c0, c1);
            #pragma unroll
            for (int d = 1; d < 64; d <<= 1) mx = fmaxf(mx, __shfl_xor(mx, d));
            const float e0 = expf(c0 - mx), e1 = expf(c1 - mx);
            float s = e0 + e1;
            #pragma unroll
            for (int d = 1; d < 64; d <<= 1) s += __shfl_xor(s, d);
            const float w0 = e0 / s, w1 = e1 / s;
            const float cww0 = __fadd_rn(__fadd_rn(__fmul_rn(wg, cwrt[j].x), omw), cwluv[j].x);
            const float cww1 = __fadd_rn(__fadd_rn(__fmul_rn(wg, cwrt[j].y), omw), cwluv[j].y);
            const float cu0 = __fadd_rn(__fadd_rn(__fmul_rn(0.95f, cwutv[j].x), w0), cww0);
            const float cu1 = __fadd_rn(__fadd_rn(__fmul_rn(0.95f, cwutv[j].y), w1), cww1);
            ((float2*)(out + OUT_CWR))[(size_t)m * 64 + l] = make_float2(w0, w1);
            ((float2*)(out + OUT_CWU))[(size_t)m * 64 + l] = make_float2(cu0, cu1);
            const unsigned long long e0u = (((unsigned long long)fenc(cu0)) << 32) | (unsigned)m;
            const unsigned long long e1u = (((unsigned long long)fenc(cu1)) << 32) | (unsigned)m;
            lmin0 = (e0u < lmin0) ? e0u : lmin0;
            lmin1 = (e1u < lmin1) ? e1u : lmin1;
        }
    }
    atomicMin(&minenc[2 * l], lmin0);
    atomicMin(&minenc[2 * l + 1], lmin1);
}

// ---------------- K3: global argmin (first-occurrence) ----------------
__global__ void k_argmin(const unsigned long long* __restrict__ minenc,
                         float* __restrict__ mins, unsigned* __restrict__ istar)
{
    __shared__ unsigned long long red[NB];
    const int t = threadIdx.x;
    const unsigned long long e = minenc[t];
    const unsigned enc32 = (unsigned)(e >> 32);
    mins[t] = fdec(enc32);
    red[t] = (((unsigned long long)enc32) << 32) | (unsigned)t;
    __syncthreads();
    for (int s = 64; s > 0; s >>= 1) {
        if (t < s) { const unsigned long long o = red[t + s]; if (o < red[t]) red[t] = o; }
        __syncthreads();
    }
    if (t == 0) {
        const unsigned bstar = (unsigned)(red[0] & 0xFFFFFFFFu);
        istar[0] = (unsigned)(minenc[bstar] & 0xFFFFFFFFu);
    }
}

// -------- K4a: memory update + c_wlu (register-tiled: 8 slots x 4 u per thread) --------
__global__ __launch_bounds__(256, 1) void k_mem(
    const float* __restrict__ mT,
    const float* __restrict__ cwr_t, const float* __restrict__ cwlu_t,
    const float* __restrict__ wgp, const float* __restrict__ mins,
    const unsigned* __restrict__ istar_p, float* __restrict__ out)
{
    __shared__ float key[NB][NU];   // 128 KB, [b][u]
    __shared__ float cww[32][NB];   // 16 KB, one 32-slot pass
    __shared__ float minsb[NB];
    const int t = threadIdx.x, w = t >> 6, l = t & 63;
    const int u0 = l * 4;
    const int sl = t >> 3, sb = (t & 7) * 16;

    for (int i = t; i < NB * NU / 4; i += 256)
        ((float4*)key)[i] = ((const float4*)(out + OUT_KEY))[i];
    if (t < NB) minsb[t] = mins[t];

    const float wg = sigm(wgp[0]);
    const float omw = __fsub_rn(1.f, wg);
    const int istar = (int)istar_p[0];
    const int base = blockIdx.x * 256;

    // prefetch staging + m rows for pass 0
    float4 wr[4], lu[4], wu[4], pm[8];
    #pragma unroll
    for (int k = 0; k < 4; ++k) {
        const size_t row = (size_t)(base + sl) * NB + sb + 4 * k;
        wr[k] = *(const float4*)(cwr_t + row);
        lu[k] = *(const float4*)(cwlu_t + row);
        wu[k] = *(const float4*)(out + OUT_CWU + row);
    }
    #pragma unroll
    for (int j = 0; j < 8; ++j)
        pm[j] = *(const float4*)(mT + (size_t)(base + w * 8 + j) * NU + u0);
    __syncthreads();    // key/minsb staged

    for (int p = 0; p < 8; ++p) {
        const int sp = base + p * 32;
        // phase A: cww -> LDS, c_wlu -> global
        #pragma unroll
        for (int k = 0; k < 4; ++k) {
            float4 cw;
            cw.x = __fadd_rn(__fadd_rn(__fmul_rn(wg, wr[k].x), omw), lu[k].x);
            cw.y = __fadd_rn(__fadd_rn(__fmul_rn(wg, wr[k].y), omw), lu[k].y);
            cw.z = __fadd_rn(__fadd_rn(__fmul_rn(wg, wr[k].z), omw), lu[k].z);
            cw.w = __fadd_rn(__fadd_rn(__fmul_rn(wg, wr[k].w), omw), lu[k].w);
            *(float4*)&cww[sl][sb + 4 * k] = cw;
            const float4 mb = *(const float4*)&minsb[sb + 4 * k];
            float4 wl;
            wl.x = (wu[k].x <= mb.x) ? 1.f : 0.f;
            wl.y = (wu[k].y <= mb.y) ? 1.f : 0.f;
            wl.z = (wu[k].z <= mb.z) ? 1.f : 0.f;
            wl.w = (wu[k].w <= mb.w) ? 1.f : 0.f;
            *(float4*)(out + OUT_CWLU + (size_t)(sp + sl) * NB + sb + 4 * k) = wl;
        }
        __syncthreads();    // cww ready
        // phase B: prefetch next pass (hidden under hot loop)
        float4 pmn[8];
        if (p < 7) {
            #pragma unroll
            for (int k = 0; k < 4; ++k) {
                const size_t row = (size_t)(sp + 32 + sl) * NB + sb + 4 * k;
                wr[k] = *(const float4*)(cwr_t + row);
                lu[k] = *(const float4*)(cwlu_t + row);
                wu[k] = *(const float4*)(out + OUT_CWU + row);
            }
            #pragma unroll
            for (int j = 0; j < 8; ++j)
                pmn[j] = *(const float4*)(mT + (size_t)(sp + 32 + w * 8 + j) * NU + u0);
        }
        // hot loop: per 4-b chunk: 12 ds_read_b128 + 128 FMA
        float4 acc[8];
        #pragma unroll
        for (int j = 0; j < 8; ++j) acc[j] = make_float4(0.f, 0.f, 0.f, 0.f);
        for (int b0 = 0; b0 < NB; b0 += 4) {
            const float4 kv0 = *(const float4*)&key[b0 + 0][u0];
            const float4 kv1 = *(const float4*)&key[b0 + 1][u0];
            const float4 kv2 = *(const float4*)&key[b0 + 2][u0];
            const float4 kv3 = *(const float4*)&key[b0 + 3][u0];
            #pragma unroll
            for (int j = 0; j < 8; ++j) {
                const float4 cw = *(const float4*)&cww[w * 8 + j][b0];
                acc[j].x += cw.x * kv0.x; acc[j].y += cw.x * kv0.y; acc[j].z += cw.x * kv0.z; acc[j].w += cw.x * kv0.w;
                acc[j].x += cw.y * kv1.x; acc[j].y += cw.y * kv1.y; acc[j].z += cw.y * kv1.z; acc[j].w += cw.y * kv1.w;
                acc[j].x += cw.z * kv2.x; acc[j].y += cw.z * kv2.y; acc[j].z += cw.z * kv2.z; acc[j].w += cw.z * kv2.w;
                acc[j].x += cw.w * kv3.x; acc[j].y += cw.w * kv3.y; acc[j].z += cw.w * kv3.z; acc[j].w += cw.w * kv3.w;
            }
        }
        // epilogue: + 128*keep*m, store
        #pragma unroll
        for (int j = 0; j < 8; ++j) {
            const int s = sp + w * 8 + j;
            const float kf = (s == istar) ? 0.f : 128.f;
            float4 o;
            o.x = acc[j].x + kf * pm[j].x;
            o.y = acc[j].y + kf * pm[j].y;
            o.z = acc[j].z + kf * pm[j].z;
            o.w = acc[j].w + kf * pm[j].w;
            *(float4*)(out + OUT_MEM + (size_t)s * NU + u0) = o;
            if (p < 7) pm[j] = pmn[j];
        }
        __syncthreads();    // cww free for next phase A
    }
}

// -------- K4b: read = c_wr.T @ m_tm1, register-tiled 8b x 8u, partials in ws --------
template <int USE_PART>
__global__ __launch_bounds__(256) void k_read(
    const float* __restrict__ mT, float* __restrict__ out, float* __restrict__ part)
{
    __shared__ float m_ch[2][8][128];
    __shared__ float cwr_ch[2][8][128];
    const int t = threadIdx.x;
    const int r = blockIdx.x, ri = r >> 1, uh = r & 1;
    const int s0 = ri * 512;
    const int b0 = (t & 15) * 8, u0 = (t >> 4) * 8;
    const int ssl = t >> 5, sul = (t & 31) * 4;

    float4 acc[8][2];
    #pragma unroll
    for (int bi = 0; bi < 8; ++bi) { acc[bi][0] = make_float4(0,0,0,0); acc[bi][1] = make_float4(0,0,0,0); }

    // prefetch chunk 0
    float4 pm = *(const float4*)(mT + (size_t)(s0 + ssl) * NU + uh * 128 + sul);
    float4 pc = *(const float4*)(out + OUT_CWR + (size_t)(s0 + ssl) * NB + sul);

    for (int c = 0; c < 64; ++c) {
        const int buf = c & 1;
        *(float4*)&m_ch[buf][ssl][sul] = pm;
        *(float4*)&cwr_ch[buf][ssl][sul] = pc;
        __syncthreads();
        if (c + 1 < 64) {   // prefetch next chunk (hidden under compute)
            const size_t sn = (size_t)(s0 + (c + 1) * 8 + ssl);
            pm = *(const float4*)(mT + sn * NU + uh * 128 + sul);
            pc = *(const float4*)(out + OUT_CWR + sn * NB + sul);
        }
        #pragma unroll
        for (int sj = 0; sj < 8; ++sj) {
            const float4 ca = *(const float4*)&cwr_ch[buf][sj][b0];
            const float4 cb = *(const float4*)&cwr_ch[buf][sj][b0 + 4];
            const float4 ma = *(const float4*)&m_ch[buf][sj][u0];
            const float4 mb = *(const float4*)&m_ch[buf][sj][u0 + 4];
            const float cwa[8] = {ca.x, ca.y, ca.z, ca.w, cb.x, cb.y, cb.z, cb.w};
            #pragma unroll
            for (int bi = 0; bi < 8; ++bi) {
                acc[bi][0].x += cwa[bi] * ma.x; acc[bi][0].y += cwa[bi] * ma.y;
                acc[bi][0].z += cwa[bi] * ma.z; acc[bi][0].w += cwa[bi] * ma.w;
                acc[bi][1].x += cwa[bi] * mb.x; acc[bi][1].y += cwa[bi] * mb.y;
                acc[bi][1].z += cwa[bi] * mb.z; acc[bi][1].w += cwa[bi] * mb.w;
            }
        }
        // no trailing barrier needed: next write targets buf^1 (disjoint), next read
        // is preceded by the barrier above.
    }

    if (USE_PART) {
        float* dst = part + (size_t)r * (128 * 128);
        #pragma unroll
        for (int bi = 0; bi < 8; ++bi) {
            *(float4*)(dst + (size_t)(b0 + bi) * 128 + u0) = acc[bi][0];
            *(float4*)(dst + (size_t)(b0 + bi) * 128 + u0 + 4) = acc[bi][1];
        }
    } else {
        #pragma unroll
        for (int bi = 0; bi < 8; ++bi) {
            const float v[8] = {acc[bi][0].x, acc[bi][0].y, acc[bi][0].z, acc[bi][0].w,
                                acc[bi][1].x, acc[bi][1].y, acc[bi][1].z, acc[bi][1].w};
            #pragma unroll
            for (int q = 0; q < 8; ++q)
                atomicAdd(out + OUT_READ + (size_t)(b0 + bi) * NU + uh * 128 + u0 + q, v[q]);
        }
    }
}

// ---------------- K5: deterministic read reduction ----------------
__global__ __launch_bounds__(256) void k_redread(const float* __restrict__ part,
                                                 float* __restrict__ out)
{
    const int b = blockIdx.x, u = threadIdx.x;
    const int uh = u >> 7, ul = u & 127;
    float s = 0.f;
    #pragma unroll 4
    for (int ri = 0; ri < 128; ++ri)
        s += part[((size_t)(ri * 2 + uh) * 128 + b) * 128 + ul];
    out[OUT_READ + b * NU + u] = s;
}

extern "C" void kernel_launch(void* const* d_in, const int* in_sizes, int n_in,
                              void* d_out, int out_size, void* d_ws, size_t ws_size,
                              hipStream_t stream)
{
    const float* inputs    = (const float*)d_in[0];
    const float* r_tm1     = (const float*)d_in[1];
    const float* m_tm1     = (const float*)d_in[2];
    const float* c_wu_tm1  = (const float*)d_in[3];
    const float* c_wlu_tm1 = (const float*)d_in[4];
    const float* c_wr_tm1  = (const float*)d_in[5];
    const float* h_tm1     = (const float*)d_in[6];
    const float* cc_tm1    = (const float*)d_in[7];
    const float* Wk        = (const float*)d_in[8];
    const float* Wr        = (const float*)d_in[9];
    const float* bias      = (const float*)d_in[10];
    const float* wgate     = (const float*)d_in[11];
    float* out = (float*)d_out;
    char* ws = (char*)d_ws;

    float* klnT = (float*)(ws + WS_KLNT);
    unsigned long long* minenc = (unsigned long long*)(ws + WS_MINENC);
    float* mins = (float*)(ws + WS_MINS);
    unsigned* istar = (unsigned*)(ws + WS_ISTAR);
    float* part = (float*)(ws + WS_PART);
    const bool use_part = ws_size >= WS_PART + (size_t)256 * 128 * 128 * 4;

    hipLaunchKernelGGL(k_lstm, dim3(128), dim3(256), 0, stream,
                       inputs, r_tm1, h_tm1, cc_tm1, Wk, Wr, bias, out, klnT, minenc);
    hipLaunchKernelGGL(k_addr, dim3(256), dim3(256), 0, stream,
                       m_tm1, c_wr_tm1, c_wlu_tm1, c_wu_tm1, wgate, klnT, out, minenc);
    hipLaunchKernelGGL(k_argmin, dim3(1), dim3(128), 0, stream, minenc, mins, istar);
    hipLaunchKernelGGL(k_mem, dim3(256), dim3(256), 0, stream,
                       m_tm1, c_wr_tm1, c_wlu_tm1, wgate, mins, istar, out);
    if (use_part) {
        hipLaunchKernelGGL((k_read<1>), dim3(256), dim3(256), 0, stream, m_tm1, out, part);
        hipLaunchKernelGGL(k_redread, dim3(128), dim3(256), 0, stream, part, out);
    } else {
        hipLaunchKernelGGL((k_read<0>), dim3(256), dim3(256), 0, stream, m_tm1, out, part);
    }
}

// Round 4
// 467.074 us; speedup vs baseline: 2.0424x; 1.1241x over previous
//
#include <hip/hip_runtime.h>
#include <math.h>

#define NM 65536
#define NB 128
#define NU 256
#define ND 512

// ---- output layout (flat f32, reference return order) ----
constexpr size_t OUT_READ = 0;                      // [B,U]    32768
constexpr size_t OUT_MEM  = 32768;                  // [M,U]    16777216
constexpr size_t OUT_CWU  = OUT_MEM + 16777216;     // [M,B]    8388608
constexpr size_t OUT_CWLU = OUT_CWU + 8388608;      // [M,B]
constexpr size_t OUT_CWR  = OUT_CWLU + 8388608;     // [M,B]
constexpr size_t OUT_KEY  = OUT_CWR + 8388608;      // [B,U]
constexpr size_t OUT_CC   = OUT_KEY + 32768;        // [B,U]

// ---- ws layout (bytes) ----
constexpr size_t WS_KLNT   = 0;        // 32768 f32 (klnT[u][b])
constexpr size_t WS_MINENC = 131072;   // 128 u64
constexpr size_t WS_MINS   = 132096;   // 128 f32
constexpr size_t WS_ISTAR  = 132608;   // 1 u32
constexpr size_t WS_PART   = 135168;   // 512 * 16384 f32 read-partials (32 MB)

__device__ __forceinline__ unsigned fenc(float x) {
    unsigned u = __float_as_uint(x);
    return (u & 0x80000000u) ? ~u : (u | 0x80000000u);
}
__device__ __forceinline__ float fdec(unsigned e) {
    unsigned u = (e & 0x80000000u) ? (e ^ 0x80000000u) : ~e;
    return __uint_as_float(u);
}
__device__ __forceinline__ float sigm(float x) { return 1.0f / (1.0f + expf(-x)); }

// ---------------- K1: LSTM controller + normalized keys (UNCHANGED, numerics anchor) ----------------
__global__ __launch_bounds__(256) void k_lstm(
    const float* __restrict__ xin_g, const float* __restrict__ r_tm1,
    const float* __restrict__ h_tm1, const float* __restrict__ cc_tm1,
    const float* __restrict__ Wk, const float* __restrict__ Wr,
    const float* __restrict__ bias, float* __restrict__ out,
    float* __restrict__ klnT, unsigned long long* __restrict__ minenc)
{
    const int b = blockIdx.x, t = threadIdx.x;
    __shared__ float xin[ND + NU];
    __shared__ float hh[NU];
    __shared__ float red[NU];
    for (int k = t; k < ND; k += 256) xin[k] = xin_g[b * ND + k];
    xin[ND + t] = r_tm1[b * NU + t];
    hh[t] = h_tm1[b * NU + t];
    out[OUT_READ + b * NU + t] = 0.f;              // zero read region each launch
    if (b == 0 && t < NB) minenc[t] = ~0ULL;       // init argmin atomics
    __syncthreads();

    float zi = bias[t], zf = bias[NU + t], zc = bias[2 * NU + t], zo = bias[3 * NU + t];
    #pragma unroll 4
    for (int k = 0; k < ND + NU; ++k) {
        const float x = xin[k];
        const float* w = Wk + (size_t)k * (4 * NU);
        zi += x * w[t]; zf += x * w[NU + t]; zc += x * w[2 * NU + t]; zo += x * w[3 * NU + t];
    }
    #pragma unroll 4
    for (int k = 0; k < NU; ++k) {
        const float x = hh[k];
        const float* w = Wr + (size_t)k * (4 * NU);
        zi += x * w[t]; zf += x * w[NU + t]; zc += x * w[2 * NU + t]; zo += x * w[3 * NU + t];
    }
    const float gi = sigm(zi), gf = sigm(zf), gc = tanhf(zc), go = sigm(zo);
    const float cold = cc_tm1[b * NU + t];
    const float cn = __fadd_rn(__fmul_rn(gf, cold), __fmul_rn(gi, gc));
    const float hn = __fmul_rn(go, tanhf(cn));
    out[OUT_KEY + b * NU + t] = hn;
    out[OUT_CC + b * NU + t] = cn;
    red[t] = hn * hn;
    __syncthreads();
    for (int s = 128; s > 0; s >>= 1) { if (t < s) red[t] += red[t + s]; __syncthreads(); }
    const float nrm = sqrtf(fmaxf(red[0], 1e-12f));
    klnT[t * NB + b] = hn / nrm;   // transposed [u][b]
}

// ------------- K2: fused norm + cosine GEMM + batch-softmax + usage + min -------------
// Block = 128 slots x 128 b, K=256 in 16 chunks of 16. 64 KB LDS -> 2 blocks/CU.
// Numerics: norm phase, dot chain (ascending u), softmax trees, c_ww/c_wu chain are
// source-identical to the R2 kernel -> bit-identical outputs.
__global__ __launch_bounds__(256, 2) void k_dot(
    const float* __restrict__ mT, const float* __restrict__ klnT,
    const float* __restrict__ cwr_t, const float* __restrict__ cwlu_t,
    const float* __restrict__ cwu_t, const float* __restrict__ wgp,
    float* __restrict__ out, unsigned long long* __restrict__ minenc)
{
    __shared__ float smem[16384];      // 64 KB: stage tiles (32 KB), later dot tile [128][128]
    __shared__ float rn_s[128];
    const int t = threadIdx.x, w = t >> 6, l = t & 63;
    const int tx = t & 15, ty = t >> 4;
    const int b0 = tx * 8, s0 = ty * 8;
    const int sb = blockIdx.x * 128;

    // ---- phase 0: row norms (bit-identical to R1/R2: lane-l float4 + xor tree) ----
    #pragma unroll 4
    for (int i = 0; i < 32; ++i) {
        const int s = w * 32 + i;
        const float4 mv = *(const float4*)(mT + (size_t)(sb + s) * NU + l * 4);
        float ss = mv.x * mv.x + mv.y * mv.y + mv.z * mv.z + mv.w * mv.w;
        #pragma unroll
        for (int d = 1; d < 64; d <<= 1) ss += __shfl_xor(ss, d);
        if (l == 0) rn_s[s] = sqrtf(fmaxf(ss, 1e-12f));   // wave-private write/read
    }

    // ---- phase 1: GEMM dot[s][b] = sum_u m[s][u] * kln[u][b] ----
    // smem offsets: ms buffers at 0 / 2048 ([16 u][128 s]), kl buffers at 4096 / 6144
    const int sl = t & 127, ug = t >> 7;       // ms stage: slot sl, u-halves
    const int ku_ = t >> 4, kb = (t & 15) * 4; // kl stage

    float acc[8][8];
    #pragma unroll
    for (int i = 0; i < 8; ++i)
        #pragma unroll
        for (int j = 0; j < 8; ++j) acc[i][j] = 0.f;

    float4 gm[2], gk[2];
    #pragma unroll
    for (int i = 0; i < 2; ++i) {
        gm[i] = *(const float4*)(mT + (size_t)(sb + sl) * NU + (ug + 2 * i) * 4);
        gk[i] = *(const float4*)(klnT + (size_t)ku_ * NB + kb + i * 64);
    }
    for (int c = 0; c < 16; ++c) {
        const int mo = (c & 1) * 2048;          // ms buffer offset
        const int ko = 4096 + (c & 1) * 2048;   // kl buffer offset
        #pragma unroll
        for (int i = 0; i < 2; ++i) {
            const int uo = (ug + 2 * i) * 4;
            smem[mo + (uo + 0) * 128 + sl] = gm[i].x;
            smem[mo + (uo + 1) * 128 + sl] = gm[i].y;
            smem[mo + (uo + 2) * 128 + sl] = gm[i].z;
            smem[mo + (uo + 3) * 128 + sl] = gm[i].w;
            *(float4*)&smem[ko + ku_ * 128 + kb + i * 64] = gk[i];
        }
        __syncthreads();
        if (c < 15) {   // prefetch next chunk into registers (overlaps compute)
            const int uc = (c + 1) * 16;
            #pragma unroll
            for (int i = 0; i < 2; ++i) {
                gm[i] = *(const float4*)(mT + (size_t)(sb + sl) * NU + uc + (ug + 2 * i) * 4);
                gk[i] = *(const float4*)(klnT + (size_t)(uc + ku_) * NB + kb + i * 64);
            }
        }
        #pragma unroll 4
        for (int u = 0; u < 16; ++u) {
            const float4 sv0 = *(const float4*)&smem[mo + u * 128 + s0];
            const float4 sv1 = *(const float4*)&smem[mo + u * 128 + s0 + 4];
            const float4 kv0 = *(const float4*)&smem[ko + u * 128 + b0];
            const float4 kv1 = *(const float4*)&smem[ko + u * 128 + b0 + 4];
            const float sv[8] = {sv0.x, sv0.y, sv0.z, sv0.w, sv1.x, sv1.y, sv1.z, sv1.w};
            const float kv[8] = {kv0.x, kv0.y, kv0.z, kv0.w, kv1.x, kv1.y, kv1.z, kv1.w};
            #pragma unroll
            for (int i = 0; i < 8; ++i)
                #pragma unroll
                for (int j = 0; j < 8; ++j)
                    acc[i][j] += sv[i] * kv[j];   // single fmac chain ascending u per (s,b)
        }
        __syncthreads();
    }

    // ---- phase 2: spill dot tile to LDS (aliases stage buffers; barrier-protected) ----
    #pragma unroll
    for (int i = 0; i < 8; ++i) {
        *(float4*)&smem[(s0 + i) * 128 + b0]     = make_float4(acc[i][0], acc[i][1], acc[i][2], acc[i][3]);
        *(float4*)&smem[(s0 + i) * 128 + b0 + 4] = make_float4(acc[i][4], acc[i][5], acc[i][6], acc[i][7]);
    }
    __syncthreads();

    // ---- phase 3: per-slot softmax + usage + min (exact R2 epilogue, lane = b-pair) ----
    const float wg = sigm(wgp[0]);
    const float omw = __fsub_rn(1.f, wg);
    unsigned long long lmin0 = ~0ULL, lmin1 = ~0ULL;
    #pragma unroll 2
    for (int i = 0; i < 32; ++i) {
        const int s = w * 32 + i;
        const int m = sb + s;
        const float2 dv = *(const float2*)&smem[s * 128 + 2 * l];
        const float rnv = rn_s[s];
        const float2 wrt = ((const float2*)(cwr_t + (size_t)m * NB))[l];
        const float2 wlu = ((const float2*)(cwlu_t + (size_t)m * NB))[l];
        const float2 wut = ((const float2*)(cwu_t + (size_t)m * NB))[l];
        const float c0 = dv.x / rnv, c1 = dv.y / rnv;
        float mx = fmaxf(c0, c1);
        #pragma unroll
        for (int d = 1; d < 64; d <<= 1) mx = fmaxf(mx, __shfl_xor(mx, d));
        const float e0 = expf(c0 - mx), e1 = expf(c1 - mx);
        float sm = e0 + e1;
        #pragma unroll
        for (int d = 1; d < 64; d <<= 1) sm += __shfl_xor(sm, d);
        const float w0 = e0 / sm, w1 = e1 / sm;
        const float cww0 = __fadd_rn(__fadd_rn(__fmul_rn(wg, wrt.x), omw), wlu.x);
        const float cww1 = __fadd_rn(__fadd_rn(__fmul_rn(wg, wrt.y), omw), wlu.y);
        const float cu0 = __fadd_rn(__fadd_rn(__fmul_rn(0.95f, wut.x), w0), cww0);
        const float cu1 = __fadd_rn(__fadd_rn(__fmul_rn(0.95f, wut.y), w1), cww1);
        ((float2*)(out + OUT_CWR))[(size_t)m * 64 + l] = make_float2(w0, w1);
        ((float2*)(out + OUT_CWU))[(size_t)m * 64 + l] = make_float2(cu0, cu1);
        const unsigned long long e0u = (((unsigned long long)fenc(cu0)) << 32) | (unsigned)m;
        const unsigned long long e1u = (((unsigned long long)fenc(cu1)) << 32) | (unsigned)m;
        lmin0 = (e0u < lmin0) ? e0u : lmin0;
        lmin1 = (e1u < lmin1) ? e1u : lmin1;
    }
    atomicMin(&minenc[2 * l], lmin0);
    atomicMin(&minenc[2 * l + 1], lmin1);
}

// ---------------- K3: global argmin (first-occurrence) ----------------
__global__ void k_argmin(const unsigned long long* __restrict__ minenc,
                         float* __restrict__ mins, unsigned* __restrict__ istar)
{
    __shared__ unsigned long long red[NB];
    const int t = threadIdx.x;
    const unsigned long long e = minenc[t];
    const unsigned enc32 = (unsigned)(e >> 32);
    mins[t] = fdec(enc32);
    red[t] = (((unsigned long long)enc32) << 32) | (unsigned)t;
    __syncthreads();
    for (int s = 64; s > 0; s >>= 1) {
        if (t < s) { const unsigned long long o = red[t + s]; if (o < red[t]) red[t] = o; }
        __syncthreads();
    }
    if (t == 0) {
        const unsigned bstar = (unsigned)(red[0] & 0xFFFFFFFFu);
        istar[0] = (unsigned)(minenc[bstar] & 0xFFFFFFFFu);
    }
}

// -------- K4a: memory update + c_wlu (register-tiled: 8 slots x 4 u per thread) --------
__global__ __launch_bounds__(256, 1) void k_mem(
    const float* __restrict__ mT,
    const float* __restrict__ cwr_t, const float* __restrict__ cwlu_t,
    const float* __restrict__ wgp, const float* __restrict__ mins,
    const unsigned* __restrict__ istar_p, float* __restrict__ out)
{
    __shared__ float key[NB][NU];   // 128 KB, [b][u]
    __shared__ float cww[32][NB];   // 16 KB, one 32-slot pass
    __shared__ float minsb[NB];
    const int t = threadIdx.x, w = t >> 6, l = t & 63;
    const int u0 = l * 4;
    const int sl = t >> 3, sb = (t & 7) * 16;

    for (int i = t; i < NB * NU / 4; i += 256)
        ((float4*)key)[i] = ((const float4*)(out + OUT_KEY))[i];
    if (t < NB) minsb[t] = mins[t];

    const float wg = sigm(wgp[0]);
    const float omw = __fsub_rn(1.f, wg);
    const int istar = (int)istar_p[0];
    const int base = blockIdx.x * 256;

    // prefetch staging + m rows for pass 0
    float4 wr[4], lu[4], wu[4], pm[8];
    #pragma unroll
    for (int k = 0; k < 4; ++k) {
        const size_t row = (size_t)(base + sl) * NB + sb + 4 * k;
        wr[k] = *(const float4*)(cwr_t + row);
        lu[k] = *(const float4*)(cwlu_t + row);
        wu[k] = *(const float4*)(out + OUT_CWU + row);
    }
    #pragma unroll
    for (int j = 0; j < 8; ++j)
        pm[j] = *(const float4*)(mT + (size_t)(base + w * 8 + j) * NU + u0);
    __syncthreads();    // key/minsb staged

    for (int p = 0; p < 8; ++p) {
        const int sp = base + p * 32;
        // phase A: cww -> LDS, c_wlu -> global
        #pragma unroll
        for (int k = 0; k < 4; ++k) {
            float4 cw;
            cw.x = __fadd_rn(__fadd_rn(__fmul_rn(wg, wr[k].x), omw), lu[k].x);
            cw.y = __fadd_rn(__fadd_rn(__fmul_rn(wg, wr[k].y), omw), lu[k].y);
            cw.z = __fadd_rn(__fadd_rn(__fmul_rn(wg, wr[k].z), omw), lu[k].z);
            cw.w = __fadd_rn(__fadd_rn(__fmul_rn(wg, wr[k].w), omw), lu[k].w);
            *(float4*)&cww[sl][sb + 4 * k] = cw;
            const float4 mb = *(const float4*)&minsb[sb + 4 * k];
            float4 wl;
            wl.x = (wu[k].x <= mb.x) ? 1.f : 0.f;
            wl.y = (wu[k].y <= mb.y) ? 1.f : 0.f;
            wl.z = (wu[k].z <= mb.z) ? 1.f : 0.f;
            wl.w = (wu[k].w <= mb.w) ? 1.f : 0.f;
            *(float4*)(out + OUT_CWLU + (size_t)(sp + sl) * NB + sb + 4 * k) = wl;
        }
        __syncthreads();    // cww ready
        // phase B: prefetch next pass (hidden under hot loop)
        float4 pmn[8];
        if (p < 7) {
            #pragma unroll
            for (int k = 0; k < 4; ++k) {
                const size_t row = (size_t)(sp + 32 + sl) * NB + sb + 4 * k;
                wr[k] = *(const float4*)(cwr_t + row);
                lu[k] = *(const float4*)(cwlu_t + row);
                wu[k] = *(const float4*)(out + OUT_CWU + row);
            }
            #pragma unroll
            for (int j = 0; j < 8; ++j)
                pmn[j] = *(const float4*)(mT + (size_t)(sp + 32 + w * 8 + j) * NU + u0);
        }
        // hot loop: per 4-b chunk: 12 ds_read_b128 + 128 FMA
        float4 acc[8];
        #pragma unroll
        for (int j = 0; j < 8; ++j) acc[j] = make_float4(0.f, 0.f, 0.f, 0.f);
        for (int b0 = 0; b0 < NB; b0 += 4) {
            const float4 kv0 = *(const float4*)&key[b0 + 0][u0];
            const float4 kv1 = *(const float4*)&key[b0 + 1][u0];
            const float4 kv2 = *(const float4*)&key[b0 + 2][u0];
            const float4 kv3 = *(const float4*)&key[b0 + 3][u0];
            #pragma unroll
            for (int j = 0; j < 8; ++j) {
                const float4 cw = *(const float4*)&cww[w * 8 + j][b0];
                acc[j].x += cw.x * kv0.x; acc[j].y += cw.x * kv0.y; acc[j].z += cw.x * kv0.z; acc[j].w += cw.x * kv0.w;
                acc[j].x += cw.y * kv1.x; acc[j].y += cw.y * kv1.y; acc[j].z += cw.y * kv1.z; acc[j].w += cw.y * kv1.w;
                acc[j].x += cw.z * kv2.x; acc[j].y += cw.z * kv2.y; acc[j].z += cw.z * kv2.z; acc[j].w += cw.z * kv2.w;
                acc[j].x += cw.w * kv3.x; acc[j].y += cw.w * kv3.y; acc[j].z += cw.w * kv3.z; acc[j].w += cw.w * kv3.w;
            }
        }
        // epilogue: + 128*keep*m, store
        #pragma unroll
        for (int j = 0; j < 8; ++j) {
            const int s = sp + w * 8 + j;
            const float kf = (s == istar) ? 0.f : 128.f;
            float4 o;
            o.x = acc[j].x + kf * pm[j].x;
            o.y = acc[j].y + kf * pm[j].y;
            o.z = acc[j].z + kf * pm[j].z;
            o.w = acc[j].w + kf * pm[j].w;
            *(float4*)(out + OUT_MEM + (size_t)s * NU + u0) = o;
            if (p < 7) pm[j] = pmn[j];
        }
        __syncthreads();    // cww free for next phase A
    }
}

// -------- K4b: read = c_wr.T @ m_tm1, register-tiled 8b x 8u, partials in ws --------
template <int USE_PART>
__global__ __launch_bounds__(256) void k_read(
    const float* __restrict__ mT, float* __restrict__ out, float* __restrict__ part)
{
    __shared__ float m_ch[2][8][128];
    __shared__ float cwr_ch[2][8][128];
    const int t = threadIdx.x;
    const int r = blockIdx.x, ri = r >> 1, uh = r & 1;
    const int s0 = ri * 256;
    const int b0 = (t & 15) * 8, u0 = (t >> 4) * 8;
    const int ssl = t >> 5, sul = (t & 31) * 4;

    float4 acc[8][2];
    #pragma unroll
    for (int bi = 0; bi < 8; ++bi) { acc[bi][0] = make_float4(0,0,0,0); acc[bi][1] = make_float4(0,0,0,0); }

    // prefetch chunk 0
    float4 pm = *(const float4*)(mT + (size_t)(s0 + ssl) * NU + uh * 128 + sul);
    float4 pc = *(const float4*)(out + OUT_CWR + (size_t)(s0 + ssl) * NB + sul);

    for (int c = 0; c < 32; ++c) {
        const int buf = c & 1;
        *(float4*)&m_ch[buf][ssl][sul] = pm;
        *(float4*)&cwr_ch[buf][ssl][sul] = pc;
        __syncthreads();
        if (c + 1 < 32) {   // prefetch next chunk (hidden under compute)
            const size_t sn = (size_t)(s0 + (c + 1) * 8 + ssl);
            pm = *(const float4*)(mT + sn * NU + uh * 128 + sul);
            pc = *(const float4*)(out + OUT_CWR + sn * NB + sul);
        }
        #pragma unroll
        for (int sj = 0; sj < 8; ++sj) {
            const float4 ca = *(const float4*)&cwr_ch[buf][sj][b0];
            const float4 cb = *(const float4*)&cwr_ch[buf][sj][b0 + 4];
            const float4 ma = *(const float4*)&m_ch[buf][sj][u0];
            const float4 mb = *(const float4*)&m_ch[buf][sj][u0 + 4];
            const float cwa[8] = {ca.x, ca.y, ca.z, ca.w, cb.x, cb.y, cb.z, cb.w};
            #pragma unroll
            for (int bi = 0; bi < 8; ++bi) {
                acc[bi][0].x += cwa[bi] * ma.x; acc[bi][0].y += cwa[bi] * ma.y;
                acc[bi][0].z += cwa[bi] * ma.z; acc[bi][0].w += cwa[bi] * ma.w;
                acc[bi][1].x += cwa[bi] * mb.x; acc[bi][1].y += cwa[bi] * mb.y;
                acc[bi][1].z += cwa[bi] * mb.z; acc[bi][1].w += cwa[bi] * mb.w;
            }
        }
    }

    if (USE_PART) {
        float* dst = part + (size_t)r * (128 * 128);
        #pragma unroll
        for (int bi = 0; bi < 8; ++bi) {
            *(float4*)(dst + (size_t)(b0 + bi) * 128 + u0) = acc[bi][0];
            *(float4*)(dst + (size_t)(b0 + bi) * 128 + u0 + 4) = acc[bi][1];
        }
    } else {
        #pragma unroll
        for (int bi = 0; bi < 8; ++bi) {
            const float v[8] = {acc[bi][0].x, acc[bi][0].y, acc[bi][0].z, acc[bi][0].w,
                                acc[bi][1].x, acc[bi][1].y, acc[bi][1].z, acc[bi][1].w};
            #pragma unroll
            for (int q = 0; q < 8; ++q)
                atomicAdd(out + OUT_READ + (size_t)(b0 + bi) * NU + uh * 128 + u0 + q, v[q]);
        }
    }
}

// ---------------- K5: deterministic read reduction ----------------
__global__ __launch_bounds__(256) void k_redread(const float* __restrict__ part,
                                                 float* __restrict__ out)
{
    const int b = blockIdx.x, u = threadIdx.x;
    const int uh = u >> 7, ul = u & 127;
    float s = 0.f;
    #pragma unroll 4
    for (int ri = 0; ri < 256; ++ri)
        s += part[((size_t)(ri * 2 + uh) * 128 + b) * 128 + ul];
    out[OUT_READ + b * NU + u] = s;
}

extern "C" void kernel_launch(void* const* d_in, const int* in_sizes, int n_in,
                              void* d_out, int out_size, void* d_ws, size_t ws_size,
                              hipStream_t stream)
{
    const float* inputs    = (const float*)d_in[0];
    const float* r_tm1     = (const float*)d_in[1];
    const float* m_tm1     = (const float*)d_in[2];
    const float* c_wu_tm1  = (const float*)d_in[3];
    const float* c_wlu_tm1 = (const float*)d_in[4];
    const float* c_wr_tm1  = (const float*)d_in[5];
    const float* h_tm1     = (const float*)d_in[6];
    const float* cc_tm1    = (const float*)d_in[7];
    const float* Wk        = (const float*)d_in[8];
    const float* Wr        = (const float*)d_in[9];
    const float* bias      = (const float*)d_in[10];
    const float* wgate     = (const float*)d_in[11];
    float* out = (float*)d_out;
    char* ws = (char*)d_ws;

    float* klnT = (float*)(ws + WS_KLNT);
    unsigned long long* minenc = (unsigned long long*)(ws + WS_MINENC);
    float* mins = (float*)(ws + WS_MINS);
    unsigned* istar = (unsigned*)(ws + WS_ISTAR);
    float* part = (float*)(ws + WS_PART);
    const bool use_part = ws_size >= WS_PART + (size_t)512 * 128 * 128 * 4;

    hipLaunchKernelGGL(k_lstm, dim3(128), dim3(256), 0, stream,
                       inputs, r_tm1, h_tm1, cc_tm1, Wk, Wr, bias, out, klnT, minenc);
    hipLaunchKernelGGL(k_dot, dim3(512), dim3(256), 0, stream,
                       m_tm1, klnT, c_wr_tm1, c_wlu_tm1, c_wu_tm1, wgate, out, minenc);
    hipLaunchKernelGGL(k_argmin, dim3(1), dim3(128), 0, stream, minenc, mins, istar);
    hipLaunchKernelGGL(k_mem, dim3(256), dim3(256), 0, stream,
                       m_tm1, c_wr_tm1, c_wlu_tm1, wgate, mins, istar, out);
    if (use_part) {
        hipLaunchKernelGGL((k_read<1>), dim3(512), dim3(256), 0, stream, m_tm1, out, part);
        hipLaunchKernelGGL(k_redread, dim3(128), dim3(256), 0, stream, part, out);
    } else {
        hipLaunchKernelGGL((k_read<0>), dim3(512), dim3(256), 0, stream, m_tm1, out, part);
    }
}